// Round 1
// baseline (8005.145 us; speedup 1.0000x reference)
//
#include <hip/hip_runtime.h>
#include <math.h>

#define NN 10000
#define EE 80000
#define SDIM 18
#define HID 1024
#define NLAYERS 4
#define GHID 256

// ---------------- zero fill (float4) ----------------
__global__ void zero_kernel(float* __restrict__ p, int n4) {
    int i = blockIdx.x * 256 + threadIdx.x;
    if (i < n4) ((float4*)p)[i] = make_float4(0.f, 0.f, 0.f, 0.f);
}

// ---------------- degree (float) ----------------
__global__ void deg_kernel(const int* __restrict__ ei, float* __restrict__ degF) {
    int e = blockIdx.x * 256 + threadIdx.x;
    if (e < EE) atomicAdd(&degF[ei[EE + e]], 1.0f);
}

// ---------------- h = sin(x@pw)*cos(x@pw) ----------------
__global__ __launch_bounds__(256) void proj_kernel(const float* __restrict__ x,
                                                   const float* __restrict__ pw,
                                                   float* __restrict__ h) {
    int row = blockIdx.y;
    int col = blockIdx.x * 256 + threadIdx.x;
    __shared__ float xr[SDIM];
    if (threadIdx.x < SDIM) xr[threadIdx.x] = x[row * SDIM + threadIdx.x];
    __syncthreads();
    float acc = 0.f;
#pragma unroll
    for (int k = 0; k < SDIM; ++k) acc += xr[k] * pw[k * HID + col];
    h[(size_t)row * HID + col] = sinf(acc) * cosf(acc);
}

// ---------------- W1diff = W1_top - W1_bot ----------------
__global__ void w1diff_kernel(const float* __restrict__ W1l, float* __restrict__ Wd) {
    int i = blockIdx.x * 256 + threadIdx.x;  // grid sized exactly HID*HID/256
    Wd[i] = W1l[i] - W1l[i + HID * HID];
}

// ---------------- SGEMM: C[M,N] = act(A[M,K] @ B[K,N] + rowscale*bias) ----------------
// 64x64 tile, BK=16, 256 threads, 4x4 microtile per thread.
template <int RELU>
__global__ __launch_bounds__(256) void sgemm_kernel(const float* __restrict__ A,
                                                    const float* __restrict__ B,
                                                    float* __restrict__ C,
                                                    const float* __restrict__ bias,      // nullable
                                                    const float* __restrict__ rowscale,  // nullable -> 1.0
                                                    int M, int N, int K) {
    __shared__ __align__(16) float As[16][68];
    __shared__ __align__(16) float Bs[16][68];
    int tid = threadIdx.x;
    int tx = tid & 15, ty = tid >> 4;
    int rowBase = blockIdx.y * 64, colBase = blockIdx.x * 64;
    int lrow = tid >> 2, kq = tid & 3;   // A-load mapping: 64 rows x 4 float4
    int krB = tid >> 4, cq = tid & 15;   // B-load mapping: 16 k-rows x 16 float4
    float acc[4][4] = {};

    for (int k0 = 0; k0 < K; k0 += 16) {
        float4 av = make_float4(0.f, 0.f, 0.f, 0.f);
        int ar = rowBase + lrow;
        if (ar < M) av = *(const float4*)(A + (size_t)ar * K + k0 + kq * 4);
        As[kq * 4 + 0][lrow] = av.x;
        As[kq * 4 + 1][lrow] = av.y;
        As[kq * 4 + 2][lrow] = av.z;
        As[kq * 4 + 3][lrow] = av.w;
        float4 bv = *(const float4*)(B + (size_t)(k0 + krB) * N + colBase + cq * 4);
        *(float4*)&Bs[krB][cq * 4] = bv;
        __syncthreads();
#pragma unroll
        for (int kk = 0; kk < 16; ++kk) {
            float a[4], b[4];
#pragma unroll
            for (int i = 0; i < 4; ++i) a[i] = As[kk][ty * 4 + i];
#pragma unroll
            for (int j = 0; j < 4; ++j) b[j] = Bs[kk][tx * 4 + j];
#pragma unroll
            for (int i = 0; i < 4; ++i)
#pragma unroll
                for (int j = 0; j < 4; ++j) acc[i][j] += a[i] * b[j];
        }
        __syncthreads();
    }

#pragma unroll
    for (int i = 0; i < 4; ++i) {
        int row = rowBase + ty * 4 + i;
        if (row >= M) continue;
        float rsv = rowscale ? rowscale[row] : 1.f;
#pragma unroll
        for (int j = 0; j < 4; ++j) {
            int col = colBase + tx * 4 + j;
            float v = acc[i][j];
            if (bias) v += rsv * bias[col];
            if (RELU) v = fmaxf(v, 0.f);
            C[(size_t)row * N + col] = v;
        }
    }
}

// ---------------- per-edge: S[dst] += relu(Cn[dst] + Bn[src]) ----------------
__global__ __launch_bounds__(256) void edge_kernel(const int* __restrict__ ei,
                                                   const float* __restrict__ Cn,
                                                   const float* __restrict__ Bn,
                                                   float* __restrict__ S) {
    int e = blockIdx.x;
    int src = ei[e];
    int dst = ei[EE + e];
    int c = threadIdx.x * 4;
    const float4 cv = *(const float4*)(Cn + (size_t)dst * HID + c);
    const float4 bv = *(const float4*)(Bn + (size_t)src * HID + c);
    float* sp = S + (size_t)dst * HID + c;
    atomicAdd(sp + 0, fmaxf(cv.x + bv.x, 0.f));
    atomicAdd(sp + 1, fmaxf(cv.y + bv.y, 0.f));
    atomicAdd(sp + 2, fmaxf(cv.z + bv.z, 0.f));
    atomicAdd(sp + 3, fmaxf(cv.w + bv.w, 0.f));
}

// ---------------- ghost head stage 2: sigmoid(g1 @ gw2 + gb2) ----------------
__global__ __launch_bounds__(256) void ghost_kernel(const float* __restrict__ g1,
                                                    const float* __restrict__ gw2,
                                                    const float* __restrict__ gb2,
                                                    float* __restrict__ out) {
    int row = blockIdx.x;
    int t = threadIdx.x;
    float v = g1[(size_t)row * GHID + t] * gw2[t];
#pragma unroll
    for (int o = 32; o > 0; o >>= 1) v += __shfl_down(v, o, 64);
    __shared__ float red[4];
    if ((t & 63) == 0) red[t >> 6] = v;
    __syncthreads();
    if (t == 0) {
        float s = red[0] + red[1] + red[2] + red[3] + gb2[0];
        out[row] = 1.f / (1.f + expf(-s));
    }
}

// ---------------- stable head: h @ sw + sb ----------------
__global__ void stable_kernel(const float* __restrict__ h, const float* __restrict__ sw,
                              const float* __restrict__ sb, float* __restrict__ out) {
    int idx = blockIdx.x * 256 + threadIdx.x;
    if (idx >= NN * SDIM) return;
    int row = idx / SDIM, c = idx % SDIM;
    float acc = sb[c];
    const float* hr = h + (size_t)row * HID;
    for (int k = 0; k < HID; ++k) acc += hr[k] * sw[k * SDIM + c];
    out[idx] = acc;
}

extern "C" void kernel_launch(void* const* d_in, const int* in_sizes, int n_in,
                              void* d_out, int out_size, void* d_ws, size_t ws_size,
                              hipStream_t stream) {
    const float* x   = (const float*)d_in[0];
    const int*   ei  = (const int*)d_in[1];
    const float* pw  = (const float*)d_in[2];
    const float* W1  = (const float*)d_in[3];
    const float* b1  = (const float*)d_in[4];
    const float* W2  = (const float*)d_in[5];
    const float* b2  = (const float*)d_in[6];
    const float* gw1 = (const float*)d_in[7];
    const float* gb1 = (const float*)d_in[8];
    const float* gw2 = (const float*)d_in[9];
    const float* gb2 = (const float*)d_in[10];
    const float* sw  = (const float*)d_in[11];
    const float* sb  = (const float*)d_in[12];

    float* out    = (float*)d_out;
    float* ghost  = out;                  // [N,1]
    float* stable = out + NN;             // [N,18]
    float* h      = out + NN + NN * SDIM; // [N,HID] lives in d_out (final h is an output)

    float* ws   = (float*)d_ws;
    float* Cn   = ws;                             // N*HID
    float* Bn   = Cn + (size_t)NN * HID;          // N*HID
    float* S    = Bn + (size_t)NN * HID;          // N*HID
    float* Wd   = S + (size_t)NN * HID;           // HID*HID
    float* g1   = Wd + (size_t)HID * HID;         // N*GHID
    float* degF = g1 + (size_t)NN * GHID;         // N

    // degrees (b2 is zero in this setup, but keep exact semantics: +deg*b2)
    zero_kernel<<<dim3((NN / 4 + 255) / 256), 256, 0, stream>>>(degF, NN / 4);
    deg_kernel<<<dim3((EE + 255) / 256), 256, 0, stream>>>(ei, degF);

    // h0 = sin(x@pw)*cos(x@pw)
    proj_kernel<<<dim3(HID / 256, NN), 256, 0, stream>>>(x, pw, h);

    dim3 g64(HID / 64, (NN + 63) / 64);
    for (int l = 0; l < NLAYERS; ++l) {
        const float* W1l = W1 + (size_t)l * 2 * HID * HID;
        w1diff_kernel<<<dim3(HID * HID / 256), 256, 0, stream>>>(W1l, Wd);
        // Cn = h @ (W1top - W1bot) + b1   (b1 folded here)
        sgemm_kernel<0><<<g64, 256, 0, stream>>>(h, Wd, Cn, b1 + (size_t)l * HID, nullptr, NN, HID, HID);
        // Bn = h @ W1bot
        sgemm_kernel<0><<<g64, 256, 0, stream>>>(h, W1l + (size_t)HID * HID, Bn, nullptr, nullptr, NN, HID, HID);
        // S = segment_sum(relu(Cn[dst] + Bn[src]), dst)
        zero_kernel<<<dim3(((NN * HID) / 4 + 255) / 256), 256, 0, stream>>>(S, (NN * HID) / 4);
        edge_kernel<<<dim3(EE), 256, 0, stream>>>(ei, Cn, Bn, S);
        // h = relu(S @ W2 + deg*b2)
        sgemm_kernel<1><<<g64, 256, 0, stream>>>(S, W2 + (size_t)l * HID * HID, h,
                                                 b2 + (size_t)l * HID, degF, NN, HID, HID);
    }

    // ghost head: g1 = relu(h @ gw1 + gb1); ghost = sigmoid(g1 @ gw2 + gb2)
    sgemm_kernel<1><<<dim3(GHID / 64, (NN + 63) / 64), 256, 0, stream>>>(h, gw1, g1, gb1, nullptr, NN, GHID, HID);
    ghost_kernel<<<dim3(NN), 256, 0, stream>>>(g1, gw2, gb2, ghost);
    // stable head
    stable_kernel<<<dim3((NN * SDIM + 255) / 256), 256, 0, stream>>>(h, sw, sb, stable);
}

// Round 2
// 3931.541 us; speedup vs baseline: 2.0361x; 2.0361x over previous
//
#include <hip/hip_runtime.h>
#include <math.h>

#define NN 10000
#define EE 80000
#define SDIM 18
#define HID 1024
#define NLAYERS 4
#define GHID 256

// ---------------- zero fill (ints) ----------------
__global__ void zeroi_kernel(int* __restrict__ p, int n) {
    int i = blockIdx.x * 256 + threadIdx.x;
    if (i < n) p[i] = 0;
}

// ---------------- CSR build: count ----------------
__global__ void count_kernel(const int* __restrict__ ei, int* __restrict__ cnt) {
    int e = blockIdx.x * 256 + threadIdx.x;
    if (e < EE) atomicAdd(&cnt[ei[EE + e]], 1);
}

// ---------------- CSR build: exclusive scan over NN counts (single block) ----------------
// Also emits cursor copy (for scatter) and degF (float degrees, for deg*b2 term).
__global__ __launch_bounds__(256) void scan_kernel(const int* __restrict__ cnt,
                                                   int* __restrict__ offs,
                                                   int* __restrict__ cursor,
                                                   float* __restrict__ degF) {
    const int CH = 40;  // 256*40 = 10240 >= NN
    __shared__ int partial[256];
    int t = threadIdx.x;
    int base = t * CH;
    int local[CH];
    int sum = 0;
#pragma unroll
    for (int i = 0; i < CH; ++i) {
        int idx = base + i;
        int v = (idx < NN) ? cnt[idx] : 0;
        local[i] = sum;
        sum += v;
    }
    partial[t] = sum;
    __syncthreads();
    for (int off = 1; off < 256; off <<= 1) {
        int v = (t >= off) ? partial[t - off] : 0;
        __syncthreads();
        partial[t] += v;
        __syncthreads();
    }
    int excl = (t == 0) ? 0 : partial[t - 1];
#pragma unroll
    for (int i = 0; i < CH; ++i) {
        int idx = base + i;
        if (idx < NN) {
            int o = excl + local[i];
            offs[idx] = o;
            cursor[idx] = o;
            degF[idx] = (float)cnt[idx];
        }
    }
    if (t == 255) offs[NN] = partial[255];
}

// ---------------- CSR build: scatter edge sources ----------------
__global__ void scatter_kernel(const int* __restrict__ ei, int* __restrict__ cursor,
                               int* __restrict__ esrc) {
    int e = blockIdx.x * 256 + threadIdx.x;
    if (e < EE) {
        int dst = ei[EE + e];
        int pos = atomicAdd(&cursor[dst], 1);
        esrc[pos] = ei[e];
    }
}

// ---------------- h = sin(x@pw)*cos(x@pw) ----------------
__global__ __launch_bounds__(256) void proj_kernel(const float* __restrict__ x,
                                                   const float* __restrict__ pw,
                                                   float* __restrict__ h) {
    int row = blockIdx.y;
    int col = blockIdx.x * 256 + threadIdx.x;
    __shared__ float xr[SDIM];
    if (threadIdx.x < SDIM) xr[threadIdx.x] = x[row * SDIM + threadIdx.x];
    __syncthreads();
    float acc = 0.f;
#pragma unroll
    for (int k = 0; k < SDIM; ++k) acc += xr[k] * pw[k * HID + col];
    h[(size_t)row * HID + col] = sinf(acc) * cosf(acc);
}

// ---------------- W1diff = W1_top - W1_bot ----------------
__global__ void w1diff_kernel(const float* __restrict__ W1l, float* __restrict__ Wd) {
    int i = blockIdx.x * 256 + threadIdx.x;  // grid sized exactly HID*HID/256
    Wd[i] = W1l[i] - W1l[i + HID * HID];
}

// ---------------- SGEMM: C[M,N] = act(A[M,K] @ B[K,N] + rowscale*bias) ----------------
template <int RELU>
__global__ __launch_bounds__(256) void sgemm_kernel(const float* __restrict__ A,
                                                    const float* __restrict__ B,
                                                    float* __restrict__ C,
                                                    const float* __restrict__ bias,
                                                    const float* __restrict__ rowscale,
                                                    int M, int N, int K) {
    __shared__ __align__(16) float As[16][68];
    __shared__ __align__(16) float Bs[16][68];
    int tid = threadIdx.x;
    int tx = tid & 15, ty = tid >> 4;
    int rowBase = blockIdx.y * 64, colBase = blockIdx.x * 64;
    int lrow = tid >> 2, kq = tid & 3;
    int krB = tid >> 4, cq = tid & 15;
    float acc[4][4] = {};

    for (int k0 = 0; k0 < K; k0 += 16) {
        float4 av = make_float4(0.f, 0.f, 0.f, 0.f);
        int ar = rowBase + lrow;
        if (ar < M) av = *(const float4*)(A + (size_t)ar * K + k0 + kq * 4);
        As[kq * 4 + 0][lrow] = av.x;
        As[kq * 4 + 1][lrow] = av.y;
        As[kq * 4 + 2][lrow] = av.z;
        As[kq * 4 + 3][lrow] = av.w;
        float4 bv = *(const float4*)(B + (size_t)(k0 + krB) * N + colBase + cq * 4);
        *(float4*)&Bs[krB][cq * 4] = bv;
        __syncthreads();
#pragma unroll
        for (int kk = 0; kk < 16; ++kk) {
            float a[4], b[4];
#pragma unroll
            for (int i = 0; i < 4; ++i) a[i] = As[kk][ty * 4 + i];
#pragma unroll
            for (int j = 0; j < 4; ++j) b[j] = Bs[kk][tx * 4 + j];
#pragma unroll
            for (int i = 0; i < 4; ++i)
#pragma unroll
                for (int j = 0; j < 4; ++j) acc[i][j] += a[i] * b[j];
        }
        __syncthreads();
    }

#pragma unroll
    for (int i = 0; i < 4; ++i) {
        int row = rowBase + ty * 4 + i;
        if (row >= M) continue;
        float rsv = rowscale ? rowscale[row] : 1.f;
#pragma unroll
        for (int j = 0; j < 4; ++j) {
            int col = colBase + tx * 4 + j;
            float v = acc[i][j];
            if (bias) v += rsv * bias[col];
            if (RELU) v = fmaxf(v, 0.f);
            C[(size_t)row * N + col] = v;
        }
    }
}

// ---------------- CSR aggregation: S[i,:] = sum_e relu(Cn[i,:] + Bn[src_e,:]) ----------------
// one block per destination node; 256 threads x float4 = 1024 cols; no atomics.
__global__ __launch_bounds__(256) void gather_kernel(const int* __restrict__ offs,
                                                     const int* __restrict__ esrc,
                                                     const float* __restrict__ Cn,
                                                     const float* __restrict__ Bn,
                                                     float* __restrict__ S) {
    int node = blockIdx.x;
    int c = threadIdx.x * 4;
    int k0 = offs[node], k1 = offs[node + 1];
    const float4 cv = *(const float4*)(Cn + (size_t)node * HID + c);
    float4 acc = make_float4(0.f, 0.f, 0.f, 0.f);
    for (int k = k0; k < k1; ++k) {
        int s = esrc[k];
        const float4 bv = *(const float4*)(Bn + (size_t)s * HID + c);
        acc.x += fmaxf(cv.x + bv.x, 0.f);
        acc.y += fmaxf(cv.y + bv.y, 0.f);
        acc.z += fmaxf(cv.z + bv.z, 0.f);
        acc.w += fmaxf(cv.w + bv.w, 0.f);
    }
    *(float4*)(S + (size_t)node * HID + c) = acc;
}

// ---------------- ghost head stage 2: sigmoid(g1 @ gw2 + gb2) ----------------
__global__ __launch_bounds__(256) void ghost_kernel(const float* __restrict__ g1,
                                                    const float* __restrict__ gw2,
                                                    const float* __restrict__ gb2,
                                                    float* __restrict__ out) {
    int row = blockIdx.x;
    int t = threadIdx.x;
    float v = g1[(size_t)row * GHID + t] * gw2[t];
#pragma unroll
    for (int o = 32; o > 0; o >>= 1) v += __shfl_down(v, o, 64);
    __shared__ float red[4];
    if ((t & 63) == 0) red[t >> 6] = v;
    __syncthreads();
    if (t == 0) {
        float s = red[0] + red[1] + red[2] + red[3] + gb2[0];
        out[row] = 1.f / (1.f + expf(-s));
    }
}

// ---------------- stable head: h @ sw + sb ----------------
__global__ void stable_kernel(const float* __restrict__ h, const float* __restrict__ sw,
                              const float* __restrict__ sb, float* __restrict__ out) {
    int idx = blockIdx.x * 256 + threadIdx.x;
    if (idx >= NN * SDIM) return;
    int row = idx / SDIM, c = idx % SDIM;
    float acc = sb[c];
    const float* hr = h + (size_t)row * HID;
    for (int k = 0; k < HID; ++k) acc += hr[k] * sw[k * SDIM + c];
    out[idx] = acc;
}

extern "C" void kernel_launch(void* const* d_in, const int* in_sizes, int n_in,
                              void* d_out, int out_size, void* d_ws, size_t ws_size,
                              hipStream_t stream) {
    const float* x   = (const float*)d_in[0];
    const int*   ei  = (const int*)d_in[1];
    const float* pw  = (const float*)d_in[2];
    const float* W1  = (const float*)d_in[3];
    const float* b1  = (const float*)d_in[4];
    const float* W2  = (const float*)d_in[5];
    const float* b2  = (const float*)d_in[6];
    const float* gw1 = (const float*)d_in[7];
    const float* gb1 = (const float*)d_in[8];
    const float* gw2 = (const float*)d_in[9];
    const float* gb2 = (const float*)d_in[10];
    const float* sw  = (const float*)d_in[11];
    const float* sb  = (const float*)d_in[12];

    float* out    = (float*)d_out;
    float* ghost  = out;                  // [N,1]
    float* stable = out + NN;             // [N,18]
    float* h      = out + NN + NN * SDIM; // [N,HID] (final h is an output)

    float* ws   = (float*)d_ws;
    float* Cn   = ws;                             // N*HID
    float* Bn   = Cn + (size_t)NN * HID;          // N*HID
    float* S    = Bn + (size_t)NN * HID;          // N*HID
    float* Wd   = S + (size_t)NN * HID;           // HID*HID
    float* g1   = Wd + (size_t)HID * HID;         // N*GHID
    float* degF = g1 + (size_t)NN * GHID;         // N
    int*   cnt    = (int*)(degF + NN);            // N
    int*   offs   = cnt + NN;                     // N+1
    int*   cursor = offs + NN + 1;                // N
    int*   esrc   = cursor + NN;                  // E

    // ---- CSR build (edge_index is constant across layers) ----
    zeroi_kernel<<<dim3((NN + 255) / 256), 256, 0, stream>>>(cnt, NN);
    count_kernel<<<dim3((EE + 255) / 256), 256, 0, stream>>>(ei, cnt);
    scan_kernel<<<dim3(1), 256, 0, stream>>>(cnt, offs, cursor, degF);
    scatter_kernel<<<dim3((EE + 255) / 256), 256, 0, stream>>>(ei, cursor, esrc);

    // h0 = sin(x@pw)*cos(x@pw)
    proj_kernel<<<dim3(HID / 256, NN), 256, 0, stream>>>(x, pw, h);

    dim3 g64(HID / 64, (NN + 63) / 64);
    for (int l = 0; l < NLAYERS; ++l) {
        const float* W1l = W1 + (size_t)l * 2 * HID * HID;
        w1diff_kernel<<<dim3(HID * HID / 256), 256, 0, stream>>>(W1l, Wd);
        // Cn = h @ (W1top - W1bot) + b1
        sgemm_kernel<0><<<g64, 256, 0, stream>>>(h, Wd, Cn, b1 + (size_t)l * HID, nullptr, NN, HID, HID);
        // Bn = h @ W1bot
        sgemm_kernel<0><<<g64, 256, 0, stream>>>(h, W1l + (size_t)HID * HID, Bn, nullptr, nullptr, NN, HID, HID);
        // S = segment_sum(relu(Cn[dst] + Bn[src]), dst)  -- CSR, no atomics
        gather_kernel<<<dim3(NN), 256, 0, stream>>>(offs, esrc, Cn, Bn, S);
        // h = relu(S @ W2 + deg*b2)
        sgemm_kernel<1><<<g64, 256, 0, stream>>>(S, W2 + (size_t)l * HID * HID, h,
                                                 b2 + (size_t)l * HID, degF, NN, HID, HID);
    }

    // ghost head
    sgemm_kernel<1><<<dim3(GHID / 64, (NN + 63) / 64), 256, 0, stream>>>(h, gw1, g1, gb1, nullptr, NN, GHID, HID);
    ghost_kernel<<<dim3(NN), 256, 0, stream>>>(g1, gw2, gb2, ghost);
    // stable head
    stable_kernel<<<dim3((NN * SDIM + 255) / 256), 256, 0, stream>>>(h, sw, sb, stable);
}

// Round 3
// 934.823 us; speedup vs baseline: 8.5633x; 4.2057x over previous
//
#include <hip/hip_runtime.h>
#include <hip/hip_bf16.h>
#include <math.h>

#define NN 10000
#define EE 80000
#define SDIM 18
#define HID 1024
#define NLAYERS 4
#define GHID 256

typedef __bf16 bf16;
typedef __bf16 bf16x8 __attribute__((ext_vector_type(8)));
typedef __bf16 bf16x4 __attribute__((ext_vector_type(4)));
typedef float f32x4 __attribute__((ext_vector_type(4)));

#define AS1C(p) ((const __attribute__((address_space(1))) void*)(p))
#define AS3(p)  ((__attribute__((address_space(3))) void*)(p))

// ---------------- zero fill (ints) ----------------
__global__ void zeroi_kernel(int* __restrict__ p, int n) {
    int i = blockIdx.x * 256 + threadIdx.x;
    if (i < n) p[i] = 0;
}

// ---------------- CSR build: count ----------------
__global__ void count_kernel(const int* __restrict__ ei, int* __restrict__ cnt) {
    int e = blockIdx.x * 256 + threadIdx.x;
    if (e < EE) atomicAdd(&cnt[ei[EE + e]], 1);
}

// ---------------- CSR build: exclusive scan (single block) ----------------
__global__ __launch_bounds__(256) void scan_kernel(const int* __restrict__ cnt,
                                                   int* __restrict__ offs,
                                                   int* __restrict__ cursor,
                                                   float* __restrict__ degF) {
    const int CH = 40;  // 256*40 = 10240 >= NN
    __shared__ int partial[256];
    int t = threadIdx.x;
    int base = t * CH;
    int local[CH];
    int sum = 0;
#pragma unroll
    for (int i = 0; i < CH; ++i) {
        int idx = base + i;
        int v = (idx < NN) ? cnt[idx] : 0;
        local[i] = sum;
        sum += v;
    }
    partial[t] = sum;
    __syncthreads();
    for (int off = 1; off < 256; off <<= 1) {
        int v = (t >= off) ? partial[t - off] : 0;
        __syncthreads();
        partial[t] += v;
        __syncthreads();
    }
    int excl = (t == 0) ? 0 : partial[t - 1];
#pragma unroll
    for (int i = 0; i < CH; ++i) {
        int idx = base + i;
        if (idx < NN) {
            int o = excl + local[i];
            offs[idx] = o;
            cursor[idx] = o;
            degF[idx] = (float)cnt[idx];
        }
    }
    if (t == 255) offs[NN] = partial[255];
}

// ---------------- CSR build: scatter edge sources ----------------
__global__ void scatter_kernel(const int* __restrict__ ei, int* __restrict__ cursor,
                               int* __restrict__ esrc) {
    int e = blockIdx.x * 256 + threadIdx.x;
    if (e < EE) {
        int dst = ei[EE + e];
        int pos = atomicAdd(&cursor[dst], 1);
        esrc[pos] = ei[e];
    }
}

// ---------------- weight transpose+convert: dst[N][M] bf16 = src[M][N] fp32 ----------------
// (optionally src - src[+HID*HID] for the W1top-W1bot fold); batched over blockIdx.z layers
template <int DIFF>
__global__ __launch_bounds__(256) void tconv_kernel(const float* __restrict__ src, long sstride,
                                                    bf16* __restrict__ dst, long dstride,
                                                    int M, int N) {
    __shared__ float t[32][33];
    const float* s = src + (size_t)blockIdx.z * sstride;
    bf16* d = dst + (size_t)blockIdx.z * dstride;
    int bx = blockIdx.x * 32;  // N (src col) base
    int by = blockIdx.y * 32;  // M (src row) base
    int tx = threadIdx.x, ty = threadIdx.y;  // (32,8)
#pragma unroll
    for (int r = 0; r < 4; ++r) {
        int row = by + ty + r * 8;
        float v = s[(size_t)row * N + bx + tx];
        if (DIFF) v -= s[(size_t)row * N + bx + tx + (size_t)HID * HID];
        t[ty + r * 8][tx] = v;
    }
    __syncthreads();
#pragma unroll
    for (int r = 0; r < 4; ++r) {
        int orow = bx + ty + r * 8;  // N index
        d[(size_t)orow * M + by + tx] = (bf16)t[tx][ty + r * 8];
    }
}

// ---------------- h0 = sin(x@pw)*cos(x@pw) -> bf16 ----------------
__global__ __launch_bounds__(256) void proj_kernel(const float* __restrict__ x,
                                                   const float* __restrict__ pw,
                                                   bf16* __restrict__ hb) {
    int row = blockIdx.y;
    int col = blockIdx.x * 256 + threadIdx.x;
    __shared__ float xr[SDIM];
    if (threadIdx.x < SDIM) xr[threadIdx.x] = x[row * SDIM + threadIdx.x];
    __syncthreads();
    float acc = 0.f;
#pragma unroll
    for (int k = 0; k < SDIM; ++k) acc += xr[k] * pw[k * HID + col];
    hb[(size_t)row * HID + col] = (bf16)(sinf(acc) * cosf(acc));
}

// ---------------- bf16 MFMA GEMM (m97 structure): C = act(A @ Bt^T + rs*bias) ----------------
// A: [M][K] bf16 row-major. Bt: [N][K] bf16 (i.e. B transposed). 128x128 tile, BK=32,
// 256 thr = 4 waves in 2x2, each wave 64x64 via 4x4 of 16x16x32 MFMA. fp32 accum.
template <int RELU, int HAS_BIAS, int HAS_RS, int WF32, int WB16>
__global__ __launch_bounds__(256) void mgemm_kernel(const bf16* __restrict__ A,
                                                    const bf16* __restrict__ Bt,
                                                    float* __restrict__ C,
                                                    bf16* __restrict__ Cb,
                                                    const float* __restrict__ bias,
                                                    const float* __restrict__ rowscale,
                                                    int M, int N, int K) {
    __shared__ bf16 As[128 * 32];
    __shared__ bf16 Bs[128 * 32];
    const int tid = threadIdx.x;
    const int m0 = blockIdx.y * 128;
    const int n0 = blockIdx.x * 128;
    const int wave = tid >> 6;
    const int wr = (wave >> 1) * 64, wc = (wave & 1) * 64;
    const int lane = tid & 63;
    const int quad = lane >> 4, r15 = lane & 15;

    f32x4 acc[4][4] = {};

    // staging slots: slot s (0..511) covers tile-row s>>2, 16B k-segment s&3
    const int s0 = tid, s1 = 256 + tid;
    int ar0 = m0 + (s0 >> 2); ar0 = ar0 < M ? ar0 : M - 1;
    int ar1 = m0 + (s1 >> 2); ar1 = ar1 < M ? ar1 : M - 1;
    const bf16* ga0 = A + (size_t)ar0 * K + (s0 & 3) * 8;
    const bf16* ga1 = A + (size_t)ar1 * K + (s1 & 3) * 8;
    const bf16* gb0 = Bt + (size_t)(n0 + (s0 >> 2)) * K + (s0 & 3) * 8;
    const bf16* gb1 = Bt + (size_t)(n0 + (s1 >> 2)) * K + (s1 & 3) * 8;
    // wave-uniform LDS bases (HW writes lane*16B from these)
    bf16* lA0 = As + (size_t)(tid & ~63) * 8;
    bf16* lA1 = As + (size_t)(256 + (tid & ~63)) * 8;
    bf16* lB0 = Bs + (size_t)(tid & ~63) * 8;
    bf16* lB1 = Bs + (size_t)(256 + (tid & ~63)) * 8;

    for (int k0 = 0; k0 < K; k0 += 32) {
        __syncthreads();
        __builtin_amdgcn_global_load_lds(AS1C(ga0 + k0), AS3(lA0), 16, 0, 0);
        __builtin_amdgcn_global_load_lds(AS1C(ga1 + k0), AS3(lA1), 16, 0, 0);
        __builtin_amdgcn_global_load_lds(AS1C(gb0 + k0), AS3(lB0), 16, 0, 0);
        __builtin_amdgcn_global_load_lds(AS1C(gb1 + k0), AS3(lB1), 16, 0, 0);
        __syncthreads();
        bf16x8 af[4], bfr[4];
#pragma unroll
        for (int i = 0; i < 4; ++i)
            af[i] = *(const bf16x8*)(As + (wr + i * 16 + r15) * 32 + quad * 8);
#pragma unroll
        for (int j = 0; j < 4; ++j)
            bfr[j] = *(const bf16x8*)(Bs + (wc + j * 16 + r15) * 32 + quad * 8);
#pragma unroll
        for (int i = 0; i < 4; ++i)
#pragma unroll
            for (int j = 0; j < 4; ++j)
                acc[i][j] = __builtin_amdgcn_mfma_f32_16x16x32_bf16(af[i], bfr[j], acc[i][j], 0, 0, 0);
    }

    // epilogue: C/D layout col=lane&15, row=quad*4+reg (m89-verified)
#pragma unroll
    for (int i = 0; i < 4; ++i) {
#pragma unroll
        for (int r = 0; r < 4; ++r) {
            int grow = m0 + wr + i * 16 + quad * 4 + r;
            if (grow >= M) continue;
            float rs = HAS_RS ? rowscale[grow] : 1.f;
#pragma unroll
            for (int j = 0; j < 4; ++j) {
                int gcol = n0 + wc + j * 16 + r15;
                float v = acc[i][j][r];
                if (HAS_BIAS) v += rs * bias[gcol];
                if (RELU) v = fmaxf(v, 0.f);
                if (WF32) C[(size_t)grow * N + gcol] = v;
                if (WB16) Cb[(size_t)grow * N + gcol] = (bf16)v;
            }
        }
    }
}

// ---------------- CSR aggregation: Sb[i,:] = sum_e relu(Cn[i,:] + Bn[src_e,:]) ----------------
__global__ __launch_bounds__(256) void gather_kernel(const int* __restrict__ offs,
                                                     const int* __restrict__ esrc,
                                                     const bf16* __restrict__ Cnb,
                                                     const bf16* __restrict__ Bnb,
                                                     bf16* __restrict__ Sb) {
    int node = blockIdx.x;
    int c = threadIdx.x * 4;
    int k0 = offs[node], k1 = offs[node + 1];
    bf16x4 cv = *(const bf16x4*)(Cnb + (size_t)node * HID + c);
    float cx = (float)cv.x, cy = (float)cv.y, cz = (float)cv.z, cw = (float)cv.w;
    float ax = 0.f, ay = 0.f, az = 0.f, aw = 0.f;
    for (int k = k0; k < k1; ++k) {
        int s = esrc[k];
        bf16x4 bv = *(const bf16x4*)(Bnb + (size_t)s * HID + c);
        ax += fmaxf(cx + (float)bv.x, 0.f);
        ay += fmaxf(cy + (float)bv.y, 0.f);
        az += fmaxf(cz + (float)bv.z, 0.f);
        aw += fmaxf(cw + (float)bv.w, 0.f);
    }
    bf16x4 o;
    o.x = (bf16)ax; o.y = (bf16)ay; o.z = (bf16)az; o.w = (bf16)aw;
    *(bf16x4*)(Sb + (size_t)node * HID + c) = o;
}

// ---------------- ghost head stage 2: sigmoid(g1 @ gw2 + gb2) ----------------
__global__ __launch_bounds__(256) void ghost_kernel(const float* __restrict__ g1,
                                                    const float* __restrict__ gw2,
                                                    const float* __restrict__ gb2,
                                                    float* __restrict__ out) {
    int row = blockIdx.x;
    int t = threadIdx.x;
    float v = g1[(size_t)row * GHID + t] * gw2[t];
#pragma unroll
    for (int o = 32; o > 0; o >>= 1) v += __shfl_down(v, o, 64);
    __shared__ float red[4];
    if ((t & 63) == 0) red[t >> 6] = v;
    __syncthreads();
    if (t == 0) {
        float s = red[0] + red[1] + red[2] + red[3] + gb2[0];
        out[row] = 1.f / (1.f + expf(-s));
    }
}

// ---------------- stable head: h @ sw + sb ----------------
__global__ void stable_kernel(const float* __restrict__ h, const float* __restrict__ sw,
                              const float* __restrict__ sb, float* __restrict__ out) {
    int idx = blockIdx.x * 256 + threadIdx.x;
    if (idx >= NN * SDIM) return;
    int row = idx / SDIM, c = idx % SDIM;
    float acc = sb[c];
    const float* hr = h + (size_t)row * HID;
    for (int k = 0; k < HID; ++k) acc += hr[k] * sw[k * SDIM + c];
    out[idx] = acc;
}

extern "C" void kernel_launch(void* const* d_in, const int* in_sizes, int n_in,
                              void* d_out, int out_size, void* d_ws, size_t ws_size,
                              hipStream_t stream) {
    const float* x   = (const float*)d_in[0];
    const int*   ei  = (const int*)d_in[1];
    const float* pw  = (const float*)d_in[2];
    const float* W1  = (const float*)d_in[3];
    const float* b1  = (const float*)d_in[4];
    const float* W2  = (const float*)d_in[5];
    const float* b2  = (const float*)d_in[6];
    const float* gw1 = (const float*)d_in[7];
    const float* gb1 = (const float*)d_in[8];
    const float* gw2 = (const float*)d_in[9];
    const float* gb2 = (const float*)d_in[10];
    const float* sw  = (const float*)d_in[11];
    const float* sb  = (const float*)d_in[12];

    float* out    = (float*)d_out;
    float* ghost  = out;                  // [N,1]
    float* stable = out + NN;             // [N,18]
    float* h      = out + NN + NN * SDIM; // [N,HID] fp32 (final h output)

    const size_t H2 = (size_t)HID * HID;
    float* ws   = (float*)d_ws;
    float* g1   = ws;                                  // NN*GHID fp32
    float* degF = g1 + (size_t)NN * GHID;              // NN
    bf16* hb    = (bf16*)(degF + NN);                  // NN*HID
    bf16* Sb    = hb + (size_t)NN * HID;               // NN*HID
    bf16* Cnb   = Sb + (size_t)NN * HID;               // NN*HID
    bf16* Bnb   = Cnb + (size_t)NN * HID;              // NN*HID
    bf16* Wdt   = Bnb + (size_t)NN * HID;              // 4*H2 (W1top-W1bot)^T
    bf16* Wbt   = Wdt + 4 * H2;                        // 4*H2 (W1bot)^T
    bf16* W2t   = Wbt + 4 * H2;                        // 4*H2 (W2)^T
    bf16* gw1t  = W2t + 4 * H2;                        // GHID*HID
    int*  cnt    = (int*)(gw1t + (size_t)GHID * HID);
    int*  offs   = cnt + NN;
    int*  cursor = offs + NN + 1;
    int*  esrc   = cursor + NN;

    // ---- CSR build ----
    zeroi_kernel<<<dim3((NN + 255) / 256), 256, 0, stream>>>(cnt, NN);
    count_kernel<<<dim3((EE + 255) / 256), 256, 0, stream>>>(ei, cnt);
    scan_kernel<<<dim3(1), 256, 0, stream>>>(cnt, offs, cursor, degF);
    scatter_kernel<<<dim3((EE + 255) / 256), 256, 0, stream>>>(ei, cursor, esrc);

    // ---- weight transpose+convert (batched over layers) ----
    dim3 tb(32, 8);
    tconv_kernel<1><<<dim3(32, 32, 4), tb, 0, stream>>>(W1, 2 * (long)H2, Wdt, (long)H2, HID, HID);
    tconv_kernel<0><<<dim3(32, 32, 4), tb, 0, stream>>>(W1 + H2, 2 * (long)H2, Wbt, (long)H2, HID, HID);
    tconv_kernel<0><<<dim3(32, 32, 4), tb, 0, stream>>>(W2, (long)H2, W2t, (long)H2, HID, HID);
    tconv_kernel<0><<<dim3(GHID / 32, HID / 32, 1), tb, 0, stream>>>(gw1, 0, gw1t, 0, HID, GHID);

    // ---- h0 ----
    proj_kernel<<<dim3(HID / 256, NN), 256, 0, stream>>>(x, pw, hb);

    dim3 gg(HID / 128, (NN + 127) / 128);  // (8, 79)
    for (int l = 0; l < NLAYERS; ++l) {
        // Cn = h @ Wd + b1 (bf16 out)
        mgemm_kernel<0, 1, 0, 0, 1><<<gg, 256, 0, stream>>>(hb, Wdt + l * H2, nullptr, Cnb,
                                                            b1 + (size_t)l * HID, nullptr, NN, HID, HID);
        // Bn = h @ W1bot (bf16 out)
        mgemm_kernel<0, 0, 0, 0, 1><<<gg, 256, 0, stream>>>(hb, Wbt + l * H2, nullptr, Bnb,
                                                            nullptr, nullptr, NN, HID, HID);
        // S = segment_sum(relu(Cn[dst]+Bn[src]))
        gather_kernel<<<dim3(NN), 256, 0, stream>>>(offs, esrc, Cnb, Bnb, Sb);
        // h = relu(S @ W2 + deg*b2); last layer also writes fp32 h to d_out
        if (l < NLAYERS - 1)
            mgemm_kernel<1, 1, 1, 0, 1><<<gg, 256, 0, stream>>>(Sb, W2t + l * H2, nullptr, hb,
                                                                b2 + (size_t)l * HID, degF, NN, HID, HID);
        else
            mgemm_kernel<1, 1, 1, 1, 1><<<gg, 256, 0, stream>>>(Sb, W2t + l * H2, h, hb,
                                                                b2 + (size_t)l * HID, degF, NN, HID, HID);
    }

    // ---- ghost head ----
    mgemm_kernel<1, 1, 0, 1, 0><<<dim3(GHID / 128, (NN + 127) / 128), 256, 0, stream>>>(
        hb, gw1t, g1, nullptr, gb1, nullptr, NN, GHID, HID);
    ghost_kernel<<<dim3(NN), 256, 0, stream>>>(g1, gw2, gb2, ghost);
    // ---- stable head ----
    stable_kernel<<<dim3((NN * SDIM + 255) / 256), 256, 0, stream>>>(h, sw, sb, stable);
}

// Round 4
// 810.679 us; speedup vs baseline: 9.8746x; 1.1531x over previous
//
#include <hip/hip_runtime.h>
#include <hip/hip_bf16.h>
#include <math.h>

#define NN 10000
#define EE 80000
#define SDIM 18
#define HID 1024
#define NLAYERS 4
#define GHID 256

typedef __bf16 bf16;
typedef __bf16 bf16x8 __attribute__((ext_vector_type(8)));
typedef __bf16 bf16x4 __attribute__((ext_vector_type(4)));
typedef float f32x4 __attribute__((ext_vector_type(4)));

#define AS1C(p) ((const __attribute__((address_space(1))) void*)(p))
#define AS3(p)  ((__attribute__((address_space(3))) void*)(p))

// ---------------- zero fill (ints) ----------------
__global__ void zeroi_kernel(int* __restrict__ p, int n) {
    int i = blockIdx.x * 256 + threadIdx.x;
    if (i < n) p[i] = 0;
}

// ---------------- CSR build: count ----------------
__global__ void count_kernel(const int* __restrict__ ei, int* __restrict__ cnt) {
    int e = blockIdx.x * 256 + threadIdx.x;
    if (e < EE) atomicAdd(&cnt[ei[EE + e]], 1);
}

// ---------------- CSR build: exclusive scan (single block) ----------------
__global__ __launch_bounds__(256) void scan_kernel(const int* __restrict__ cnt,
                                                   int* __restrict__ offs,
                                                   int* __restrict__ cursor,
                                                   float* __restrict__ degF) {
    const int CH = 40;  // 256*40 = 10240 >= NN
    __shared__ int partial[256];
    int t = threadIdx.x;
    int base = t * CH;
    int local[CH];
    int sum = 0;
#pragma unroll
    for (int i = 0; i < CH; ++i) {
        int idx = base + i;
        int v = (idx < NN) ? cnt[idx] : 0;
        local[i] = sum;
        sum += v;
    }
    partial[t] = sum;
    __syncthreads();
    for (int off = 1; off < 256; off <<= 1) {
        int v = (t >= off) ? partial[t - off] : 0;
        __syncthreads();
        partial[t] += v;
        __syncthreads();
    }
    int excl = (t == 0) ? 0 : partial[t - 1];
#pragma unroll
    for (int i = 0; i < CH; ++i) {
        int idx = base + i;
        if (idx < NN) {
            int o = excl + local[i];
            offs[idx] = o;
            cursor[idx] = o;
            degF[idx] = (float)cnt[idx];
        }
    }
    if (t == 255) offs[NN] = partial[255];
}

// ---------------- CSR build: scatter edge sources ----------------
__global__ void scatter_kernel(const int* __restrict__ ei, int* __restrict__ cursor,
                               int* __restrict__ esrc) {
    int e = blockIdx.x * 256 + threadIdx.x;
    if (e < EE) {
        int dst = ei[EE + e];
        int pos = atomicAdd(&cursor[dst], 1);
        esrc[pos] = ei[e];
    }
}

// ---------------- fused W1 transpose: WT[l] = [(W1top-W1bot)^T ; W1bot^T] bf16 ----------------
__global__ __launch_bounds__(256) void tconvW1_kernel(const float* __restrict__ W1,
                                                      bf16* __restrict__ WT) {
    __shared__ float td[32][33];
    __shared__ float tb[32][33];
    const size_t H2 = (size_t)HID * HID;
    const float* s = W1 + (size_t)blockIdx.z * 2 * H2;
    bf16* d = WT + (size_t)blockIdx.z * 2 * H2;
    int bx = blockIdx.x * 32;  // col (n) base
    int by = blockIdx.y * 32;  // row (k) base
    int tx = threadIdx.x, ty = threadIdx.y;  // (32,8)
#pragma unroll
    for (int r = 0; r < 4; ++r) {
        int row = by + ty + r * 8;
        float vt = s[(size_t)row * HID + bx + tx];
        float vb = s[H2 + (size_t)row * HID + bx + tx];
        td[ty + r * 8][tx] = vt - vb;
        tb[ty + r * 8][tx] = vb;
    }
    __syncthreads();
#pragma unroll
    for (int r = 0; r < 4; ++r) {
        int orow = bx + ty + r * 8;  // n index
        d[(size_t)orow * HID + by + tx] = (bf16)td[tx][ty + r * 8];
        d[(size_t)(HID + orow) * HID + by + tx] = (bf16)tb[tx][ty + r * 8];
    }
}

// ---------------- generic transpose+convert: dst[N][M] bf16 = src[M][N] fp32 ----------------
__global__ __launch_bounds__(256) void tconv_kernel(const float* __restrict__ src, long sstride,
                                                    bf16* __restrict__ dst, long dstride,
                                                    int M, int N) {
    __shared__ float t[32][33];
    const float* s = src + (size_t)blockIdx.z * sstride;
    bf16* d = dst + (size_t)blockIdx.z * dstride;
    int bx = blockIdx.x * 32;
    int by = blockIdx.y * 32;
    int tx = threadIdx.x, ty = threadIdx.y;
#pragma unroll
    for (int r = 0; r < 4; ++r) {
        int row = by + ty + r * 8;
        t[ty + r * 8][tx] = s[(size_t)row * N + bx + tx];
    }
    __syncthreads();
#pragma unroll
    for (int r = 0; r < 4; ++r) {
        int orow = bx + ty + r * 8;
        d[(size_t)orow * M + by + tx] = (bf16)t[tx][ty + r * 8];
    }
}

// ---------------- swt[32][1024] bf16 = sw[1024][18]^T zero-padded ----------------
__global__ void swt_kernel(const float* __restrict__ sw, bf16* __restrict__ swt) {
    int i = blockIdx.x * 256 + threadIdx.x;  // 32*1024
    int n = i >> 10, k = i & 1023;
    swt[i] = (bf16)(n < SDIM ? sw[k * SDIM + n] : 0.f);
}

// ---------------- combined bias cb[l][2048] = [b1[l] ; 0] ----------------
__global__ void bias2_kernel(const float* __restrict__ b1, float* __restrict__ cb) {
    int i = blockIdx.x * 256 + threadIdx.x;  // 4*2048
    int l = i >> 11, c = i & 2047;
    cb[i] = (c < HID) ? b1[l * HID + c] : 0.f;
}

// ---------------- h0 = sin(x@pw)*cos(x@pw) -> bf16 ----------------
__global__ __launch_bounds__(256) void proj_kernel(const float* __restrict__ x,
                                                   const float* __restrict__ pw,
                                                   bf16* __restrict__ hb) {
    int row = blockIdx.y;
    int col = blockIdx.x * 256 + threadIdx.x;
    __shared__ float xr[SDIM];
    if (threadIdx.x < SDIM) xr[threadIdx.x] = x[row * SDIM + threadIdx.x];
    __syncthreads();
    float acc = 0.f;
#pragma unroll
    for (int k = 0; k < SDIM; ++k) acc += xr[k] * pw[k * HID + col];
    hb[(size_t)row * HID + col] = (bf16)(sinf(acc) * cosf(acc));
}

// ---------------- bf16 MFMA GEMM (m97 structure): C = act(A @ Bt^T + rs*bias) ----------------
template <int RELU, int HAS_BIAS, int HAS_RS, int WF32, int WB16>
__global__ __launch_bounds__(256) void mgemm_kernel(const bf16* __restrict__ A,
                                                    const bf16* __restrict__ Bt,
                                                    float* __restrict__ C,
                                                    bf16* __restrict__ Cb,
                                                    const float* __restrict__ bias,
                                                    const float* __restrict__ rowscale,
                                                    int M, int N, int K) {
    __shared__ bf16 As[128 * 32];
    __shared__ bf16 Bs[128 * 32];
    const int tid = threadIdx.x;
    const int m0 = blockIdx.y * 128;
    const int n0 = blockIdx.x * 128;
    const int wave = tid >> 6;
    const int wr = (wave >> 1) * 64, wc = (wave & 1) * 64;
    const int lane = tid & 63;
    const int quad = lane >> 4, r15 = lane & 15;

    f32x4 acc[4][4] = {};

    const int s0 = tid, s1 = 256 + tid;
    int ar0 = m0 + (s0 >> 2); ar0 = ar0 < M ? ar0 : M - 1;
    int ar1 = m0 + (s1 >> 2); ar1 = ar1 < M ? ar1 : M - 1;
    const bf16* ga0 = A + (size_t)ar0 * K + (s0 & 3) * 8;
    const bf16* ga1 = A + (size_t)ar1 * K + (s1 & 3) * 8;
    const bf16* gb0 = Bt + (size_t)(n0 + (s0 >> 2)) * K + (s0 & 3) * 8;
    const bf16* gb1 = Bt + (size_t)(n0 + (s1 >> 2)) * K + (s1 & 3) * 8;
    bf16* lA0 = As + (size_t)(tid & ~63) * 8;
    bf16* lA1 = As + (size_t)(256 + (tid & ~63)) * 8;
    bf16* lB0 = Bs + (size_t)(tid & ~63) * 8;
    bf16* lB1 = Bs + (size_t)(256 + (tid & ~63)) * 8;

    for (int k0 = 0; k0 < K; k0 += 32) {
        __syncthreads();
        __builtin_amdgcn_global_load_lds(AS1C(ga0 + k0), AS3(lA0), 16, 0, 0);
        __builtin_amdgcn_global_load_lds(AS1C(ga1 + k0), AS3(lA1), 16, 0, 0);
        __builtin_amdgcn_global_load_lds(AS1C(gb0 + k0), AS3(lB0), 16, 0, 0);
        __builtin_amdgcn_global_load_lds(AS1C(gb1 + k0), AS3(lB1), 16, 0, 0);
        __syncthreads();
        bf16x8 af[4], bfr[4];
#pragma unroll
        for (int i = 0; i < 4; ++i)
            af[i] = *(const bf16x8*)(As + (wr + i * 16 + r15) * 32 + quad * 8);
#pragma unroll
        for (int j = 0; j < 4; ++j)
            bfr[j] = *(const bf16x8*)(Bs + (wc + j * 16 + r15) * 32 + quad * 8);
#pragma unroll
        for (int i = 0; i < 4; ++i)
#pragma unroll
            for (int j = 0; j < 4; ++j)
                acc[i][j] = __builtin_amdgcn_mfma_f32_16x16x32_bf16(af[i], bfr[j], acc[i][j], 0, 0, 0);
    }

#pragma unroll
    for (int i = 0; i < 4; ++i) {
#pragma unroll
        for (int r = 0; r < 4; ++r) {
            int grow = m0 + wr + i * 16 + quad * 4 + r;
            if (grow >= M) continue;
            float rs = HAS_RS ? rowscale[grow] : 1.f;
#pragma unroll
            for (int j = 0; j < 4; ++j) {
                int gcol = n0 + wc + j * 16 + r15;
                float v = acc[i][j][r];
                if (HAS_BIAS) v += rs * bias[gcol];
                if (RELU) v = fmaxf(v, 0.f);
                if (WF32) C[(size_t)grow * N + gcol] = v;
                if (WB16) Cb[(size_t)grow * N + gcol] = (bf16)v;
            }
        }
    }
}

// ---------------- CSR aggregation over combined CB[node][2048] = [Cn ; Bn] ----------------
__global__ __launch_bounds__(256) void gather_kernel(const int* __restrict__ offs,
                                                     const int* __restrict__ esrc,
                                                     const bf16* __restrict__ CB,
                                                     bf16* __restrict__ Sb) {
    int node = blockIdx.x;
    int c = threadIdx.x * 4;
    int k0 = offs[node], k1 = offs[node + 1];
    bf16x4 cv = *(const bf16x4*)(CB + (size_t)node * 2048 + c);
    float cx = (float)cv.x, cy = (float)cv.y, cz = (float)cv.z, cw = (float)cv.w;
    float ax = 0.f, ay = 0.f, az = 0.f, aw = 0.f;
    for (int k = k0; k < k1; ++k) {
        int s = esrc[k];
        bf16x4 bv = *(const bf16x4*)(CB + (size_t)s * 2048 + 1024 + c);
        ax += fmaxf(cx + (float)bv.x, 0.f);
        ay += fmaxf(cy + (float)bv.y, 0.f);
        az += fmaxf(cz + (float)bv.z, 0.f);
        aw += fmaxf(cw + (float)bv.w, 0.f);
    }
    bf16x4 o;
    o.x = (bf16)ax; o.y = (bf16)ay; o.z = (bf16)az; o.w = (bf16)aw;
    *(bf16x4*)(Sb + (size_t)node * HID + c) = o;
}

// ---------------- stable head via MFMA: out[16 rows][18] = hb_tile @ swt^T + sb ----------------
// one wave per 16-row tile; A fragments straight from global (A[m=lane&15][k=quad*8+j]).
__global__ __launch_bounds__(64) void stable_mfma_kernel(const bf16* __restrict__ hb,
                                                         const bf16* __restrict__ swt,
                                                         const float* __restrict__ sb,
                                                         float* __restrict__ out) {
    int m0 = blockIdx.x * 16;  // NN = 625*16 exact
    int lane = threadIdx.x;
    int quad = lane >> 4, r15 = lane & 15;
    f32x4 acc0 = {}, acc1 = {};
    const bf16* arow = hb + (size_t)(m0 + r15) * HID + quad * 8;
    const bf16* b0 = swt + (size_t)r15 * HID + quad * 8;
    const bf16* b1p = swt + (size_t)(16 + r15) * HID + quad * 8;
    for (int k0 = 0; k0 < HID; k0 += 32) {
        bf16x8 af = *(const bf16x8*)(arow + k0);
        bf16x8 bf0 = *(const bf16x8*)(b0 + k0);
        bf16x8 bf1 = *(const bf16x8*)(b1p + k0);
        acc0 = __builtin_amdgcn_mfma_f32_16x16x32_bf16(af, bf0, acc0, 0, 0, 0);
        acc1 = __builtin_amdgcn_mfma_f32_16x16x32_bf16(af, bf1, acc1, 0, 0, 0);
    }
#pragma unroll
    for (int r = 0; r < 4; ++r) {
        int grow = m0 + quad * 4 + r;
        out[(size_t)grow * SDIM + r15] = acc0[r] + sb[r15];
        if (r15 < 2) out[(size_t)grow * SDIM + 16 + r15] = acc1[r] + sb[16 + r15];
    }
}

// ---------------- ghost head stage 2: sigmoid(g1 @ gw2 + gb2) ----------------
__global__ __launch_bounds__(256) void ghost_kernel(const float* __restrict__ g1,
                                                    const float* __restrict__ gw2,
                                                    const float* __restrict__ gb2,
                                                    float* __restrict__ out) {
    int row = blockIdx.x;
    int t = threadIdx.x;
    float v = g1[(size_t)row * GHID + t] * gw2[t];
#pragma unroll
    for (int o = 32; o > 0; o >>= 1) v += __shfl_down(v, o, 64);
    __shared__ float red[4];
    if ((t & 63) == 0) red[t >> 6] = v;
    __syncthreads();
    if (t == 0) {
        float s = red[0] + red[1] + red[2] + red[3] + gb2[0];
        out[row] = 1.f / (1.f + expf(-s));
    }
}

extern "C" void kernel_launch(void* const* d_in, const int* in_sizes, int n_in,
                              void* d_out, int out_size, void* d_ws, size_t ws_size,
                              hipStream_t stream) {
    const float* x   = (const float*)d_in[0];
    const int*   ei  = (const int*)d_in[1];
    const float* pw  = (const float*)d_in[2];
    const float* W1  = (const float*)d_in[3];
    const float* b1  = (const float*)d_in[4];
    const float* W2  = (const float*)d_in[5];
    const float* b2  = (const float*)d_in[6];
    const float* gw1 = (const float*)d_in[7];
    const float* gb1 = (const float*)d_in[8];
    const float* gw2 = (const float*)d_in[9];
    const float* gb2 = (const float*)d_in[10];
    const float* sw  = (const float*)d_in[11];
    const float* sb  = (const float*)d_in[12];

    float* out    = (float*)d_out;
    float* ghost  = out;                  // [N,1]
    float* stable = out + NN;             // [N,18]
    float* h      = out + NN + NN * SDIM; // [N,HID] fp32 (final h output)

    const size_t H2 = (size_t)HID * HID;
    float* ws   = (float*)d_ws;
    float* g1   = ws;                                  // NN*GHID fp32
    float* degF = g1 + (size_t)NN * GHID;              // NN
    float* cb   = degF + NN;                           // 4*2048 fp32
    bf16* hb    = (bf16*)(cb + 4 * 2048);              // NN*HID
    bf16* Sb    = hb + (size_t)NN * HID;               // NN*HID
    bf16* CB    = Sb + (size_t)NN * HID;               // NN*2048
    bf16* WT    = CB + (size_t)NN * 2048;              // 4 * 2*H2  ([Wd;Wb]^T per layer)
    bf16* W2t   = WT + 8 * H2;                         // 4*H2
    bf16* gw1t  = W2t + 4 * H2;                        // GHID*HID
    bf16* swt   = gw1t + (size_t)GHID * HID;           // 32*1024
    int*  cnt    = (int*)(swt + 32 * 1024);
    int*  offs   = cnt + NN;
    int*  cursor = offs + NN + 1;
    int*  esrc   = cursor + NN;

    // ---- CSR build ----
    zeroi_kernel<<<dim3((NN + 255) / 256), 256, 0, stream>>>(cnt, NN);
    count_kernel<<<dim3((EE + 255) / 256), 256, 0, stream>>>(ei, cnt);
    scan_kernel<<<dim3(1), 256, 0, stream>>>(cnt, offs, cursor, degF);
    scatter_kernel<<<dim3((EE + 255) / 256), 256, 0, stream>>>(ei, cursor, esrc);

    // ---- weight prep ----
    dim3 tb(32, 8);
    tconvW1_kernel<<<dim3(32, 32, 4), tb, 0, stream>>>(W1, WT);
    tconv_kernel<<<dim3(32, 32, 4), tb, 0, stream>>>(W2, (long)H2, W2t, (long)H2, HID, HID);
    tconv_kernel<<<dim3(GHID / 32, HID / 32, 1), tb, 0, stream>>>(gw1, 0, gw1t, 0, HID, GHID);
    swt_kernel<<<dim3(32 * 1024 / 256), 256, 0, stream>>>(sw, swt);
    bias2_kernel<<<dim3(4 * 2048 / 256), 256, 0, stream>>>(b1, cb);

    // ---- h0 ----
    proj_kernel<<<dim3(HID / 256, NN), 256, 0, stream>>>(x, pw, hb);

    dim3 gfused(2048 / 128, (NN + 127) / 128);  // (16, 79)
    dim3 gw2g(HID / 128, (NN + 127) / 128);     // (8, 79)
    for (int l = 0; l < NLAYERS; ++l) {
        // CB = hb @ [Wd ; Wb]^T + [b1 ; 0]   (N = 2048, fused Cn/Bn)
        mgemm_kernel<0, 1, 0, 0, 1><<<gfused, 256, 0, stream>>>(
            hb, WT + (size_t)l * 2 * H2, nullptr, CB, cb + l * 2048, nullptr, NN, 2048, HID);
        // S = segment_sum(relu(Cn[dst]+Bn[src]))
        gather_kernel<<<dim3(NN), 256, 0, stream>>>(offs, esrc, CB, Sb);
        // h = relu(S @ W2 + deg*b2); last layer also writes fp32 h to d_out
        if (l < NLAYERS - 1)
            mgemm_kernel<1, 1, 1, 0, 1><<<gw2g, 256, 0, stream>>>(
                Sb, W2t + (size_t)l * H2, nullptr, hb, b2 + (size_t)l * HID, degF, NN, HID, HID);
        else
            mgemm_kernel<1, 1, 1, 1, 1><<<gw2g, 256, 0, stream>>>(
                Sb, W2t + (size_t)l * H2, h, hb, b2 + (size_t)l * HID, degF, NN, HID, HID);
    }

    // ---- ghost head ----
    mgemm_kernel<1, 1, 0, 1, 0><<<dim3(GHID / 128, (NN + 127) / 128), 256, 0, stream>>>(
        hb, gw1t, g1, nullptr, gb1, nullptr, NN, GHID, HID);
    ghost_kernel<<<dim3(NN), 256, 0, stream>>>(g1, gw2, gb2, ghost);
    // ---- stable head (MFMA, 1 wave / 16 rows) ----
    stable_mfma_kernel<<<dim3(NN / 16), 64, 0, stream>>>(hb, swt, sb, stable);
}